// Round 19
// baseline (199.598 us; speedup 1.0000x reference)
//
#include <hip/hip_runtime.h>
#include <math.h>

#define N     8192
#define BS    2
#define KNN   16
#define SUP   7
#define KC    128
#define SK    (SUP*KC)   // 896
#define NCH   32
#define CH    (N/NCH)    // 256
#define SLOTS 12
#define CAP   (NCH*SLOTS) // 384 u16 slots = 768B/query
#define QG    256
#define PPB   4
#define OPB   16
#define LCAP  96          // LDS key capacity per query (incl. self)
#define LSTR  98          // padded stride (784B -> 4-bank stagger/query)
#define GR1   64          // stage-1 reduction blocks per batch (32 rows each)

typedef unsigned long long ull;
typedef unsigned short ushort4v __attribute__((ext_vector_type(4)));

__device__ __forceinline__ float dist2(float4 a, float4 b) {
    float dx = a.x - b.x, dy = a.y - b.y, dz = a.z - b.z;
    return fmaf(dx, dx, fmaf(dy, dy, dz * dz));
}

// sorted-insert chain over 16 NAMED u64 registers (fallback path only)
#define SW(Kt) { ull _lo = (Kt < _n) ? Kt : _n; ull _hi = (Kt < _n) ? _n : Kt; Kt = _lo; _n = _hi; }
#define INS16(NK) do { ull _n = (NK); if (_n < K15) { \
    SW(K0) SW(K1) SW(K2) SW(K3) SW(K4) SW(K5) SW(K6) SW(K7) \
    SW(K8) SW(K9) SW(K10) SW(K11) SW(K12) SW(K13) SW(K14) SW(K15) } } while(0)

#define DECL16 ull K0=~0ull,K1=~0ull,K2=~0ull,K3=~0ull,K4=~0ull,K5=~0ull,K6=~0ull,K7=~0ull, \
                   K8=~0ull,K9=~0ull,K10=~0ull,K11=~0ull,K12=~0ull,K13=~0ull,K14=~0ull,K15=~0ull;

// ---------------------------------------------------------------- prep
// vb4.w = |p|^2 / 2; also zeroes fbcnt (replaces the memset graph node).
__global__ void k_prep(const float* __restrict__ verts, const float* __restrict__ dirs,
                       const float* __restrict__ wste, const float* __restrict__ wconv,
                       float4* __restrict__ vb4, float4* __restrict__ sup4,
                       float4* __restrict__ wste4, float4* __restrict__ wt4,
                       int* __restrict__ fbcnt) {
    int t = blockIdx.x * blockDim.x + threadIdx.x;
    if (t < 16) fbcnt[t] = 0;
    if (t < BS * N) {
        float x = verts[t*3], y = verts[t*3+1], z = verts[t*3+2];
        vb4[t] = make_float4(x, y, z, 0.5f * fmaf(x, x, fmaf(y, y, z*z)));
    }
    int u = t - BS * N;
    if (u >= 0 && u < SK) {
        float x = dirs[u], y = dirs[SK + u], z = dirs[2*SK + u];
        float inv = 1.f / fmaxf(sqrtf(fmaf(x, x, fmaf(y, y, z*z))), 1e-12f);
        sup4[u] = make_float4(x*inv, y*inv, z*inv, 0.f);
    }
    int v = u - SK;
    if (v >= 0 && v < KC)
        wste4[v] = make_float4(wste[v*3], wste[v*3+1], wste[v*3+2], 0.f);
    int w = v - KC;
    if (w >= 0 && w < 32*KC) {
        int c4 = w >> 7, k = w & 127;
        const float* r = wconv + k*2*KC + c4*4;   // W1 half, transposed to [c4][k]
        wt4[w] = make_float4(r[0], r[1], r[2], r[3]);
    }
}

// ------------------------------------------------- calibrated per-query radius
// 16 subs/query (4 waves/SIMD). LDS sample: SB=[0,2048), SA[t]=SB[4t].
// Phase A: 32-iter sorted-4 ladders + 4-stage shfl bitonic merge -> t4.
// Phase B: 128-iter count. thr = t4 * (12/c)^(1/3): E[#pass over N] = 48.
__global__ void k_thr(const float4* __restrict__ vb4, float* __restrict__ thr) {
    __shared__ float4 SB[2048];
    __shared__ float4 SA[512];
    int b = blockIdx.y;
    int tid = threadIdx.x;
    const float4* vb = vb4 + b * N;
#pragma unroll
    for (int s = 0; s < 8; ++s)                  // coalesced 32KB stage
        SB[tid + 256*s] = vb[tid + 256*s];
    __syncthreads();
#pragma unroll
    for (int s = 0; s < 2; ++s) {                // derive phase-A subset
        int t = tid + 256*s;
        SA[t] = SB[4*t];
    }
    __syncthreads();
    int sub = tid & 15;
    int i = blockIdx.x * 16 + (tid >> 4);
    float4 q = vb[i];
    float b0 = 3.4e38f, b1 = 3.4e38f, b2 = 3.4e38f, b3 = 3.4e38f;
#pragma unroll 8
    for (int s = 0; s < 32; ++s) {
        int t = s * 16 + sub;
        float d = dist2(q, SA[t]);
        if (4*t == i) d = 3.4e38f;               // self-exclude
        float t0 = fminf(b0, d); float r = fmaxf(b0, d); b0 = t0;
        float t1 = fminf(b1, r); r = fmaxf(b1, r); b1 = t1;
        float t2 = fminf(b2, r); r = fmaxf(b2, r); b2 = t2;
        b3 = fminf(b3, r);
    }
#pragma unroll
    for (int st = 1; st < 16; st <<= 1) {        // merge sorted-4 lists across subs
        float c0 = __shfl_xor(b0, st, 64);
        float c1 = __shfl_xor(b1, st, 64);
        float c2 = __shfl_xor(b2, st, 64);
        float c3 = __shfl_xor(b3, st, 64);
        float m0 = fminf(b0, c3), m1 = fminf(b1, c2);
        float m2 = fminf(b2, c1), m3 = fminf(b3, c0);
        float x0 = fminf(m0, m2), x2 = fmaxf(m0, m2);
        float x1 = fminf(m1, m3), x3 = fmaxf(m1, m3);
        b0 = fminf(x0, x1); b1 = fmaxf(x0, x1);
        b2 = fminf(x2, x3); b3 = fmaxf(x2, x3);
    }
    float t4 = b3;
    int c = 0;
#pragma unroll 8
    for (int s = 0; s < 128; ++s) {
        int p = s * 16 + sub;
        float d = dist2(q, SB[p]);
        c += (d <= t4 && p != i) ? 1 : 0;
    }
    c += __shfl_xor(c, 1, 64);
    c += __shfl_xor(c, 2, 64);
    c += __shfl_xor(c, 4, 64);
    c += __shfl_xor(c, 8, 64);                   // c >= 4 (A-winners are in B)
    if (sub == 0) {
        float f = __powf(12.0f / (float)c, 0.3333333f);
        thr[b*N + i] = t4 * f;
    }
}

// ------------------------------------------------- filtered candidate append
// Dot-form filter: q.p - |p|^2/2 >= (|q|^2 - thr)/2  <=>  |q-p|^2 <= thr.
// SELF IS INCLUDED and excluded later in select via rank shift.
// blockIdx.y-based chunk base -> wave-uniform addresses -> scalar-pipe s_load.
__global__ void k_append(const float4* __restrict__ vb4, const float* __restrict__ thr,
                         int* __restrict__ ccnt, unsigned short* __restrict__ cand) {
    int b = blockIdx.z, qg = blockIdx.x, c = blockIdx.y;
    const float4* vb = vb4 + b * N;
    int base = c * CH;
    int i = qg * QG + threadIdx.x;
    int qi = b*N + i;
    float4 q = vb[i];
    float h = q.w - 0.5f * thr[qi];              // (|q|^2 - thr)/2
    unsigned short* mycand = cand + ((size_t)qi * NCH + c) * SLOTS;
    const float4* pts = vb + base;
    int p = 0;
#pragma unroll 8
    for (int j = 0; j < CH; ++j) {
        float4 pt = pts[j];                      // wave-uniform address -> scalar pipe
        float lhs = fmaf(q.x, pt.x, fmaf(q.y, pt.y, fmaf(q.z, pt.z, -pt.w)));
        if (lhs >= h) {
            mycand[p < SLOTS ? p : SLOTS-1] = (unsigned short)(base + j);
            p++;
        }
    }
    ccnt[qi * NCH + c] = p;                      // actual count (>SLOTS flags overflow)
}

// ------------------------------------------------- exact top-16: rank-based
// 16 subs/query (4 waves/SIMD), 2 chunks each. Phase 1: gather keys to LDS.
// Phase 2: 6 strided positions/thread; rank = #{keys < mine}. Self rank 0;
// neighbors ranks 1..16 -> oi[rank-1].
#define GRP4W(CP, SOFF) { \
    ushort4v gv = *(const ushort4v*)((CP) + (SOFF)); \
    int jj[4]; \
    _Pragma("unroll") for (int s = 0; s < 4; ++s) jj[s] = (int)gv[s]; \
    float4 pv[4]; \
    _Pragma("unroll") for (int s = 0; s < 4; ++s) pv[s] = vb[jj[s] & (N-1)]; \
    _Pragma("unroll") for (int s = 0; s < 4; ++s) { \
        if ((SOFF + s) < nc) { \
            float d = dist2(q, pv[s]); \
            lkeys[kb + off + SOFF + s] = ((ull)__float_as_uint(d) << 32) | (unsigned)jj[s]; \
        } \
    } }

__global__ void k_select(const float4* __restrict__ vb4, const int* __restrict__ ccnt,
                         const unsigned short* __restrict__ cand, int* __restrict__ idxout,
                         int* __restrict__ fbcnt, int* __restrict__ fblist) {
    __shared__ ull lkeys[16 * LSTR];             // 12.25 KB
    int b = blockIdx.y;
    int tid = threadIdx.x;
    int sub = tid & 15;
    int ql = tid >> 4;                           // 0..15
    int i = blockIdx.x * 16 + ql;
    int qi = b*N + i;
    int kb = ql * LSTR;
    int c0 = 2*sub;

    int total = 0, mx = 0, off0 = 0;
#pragma unroll
    for (int c4 = 0; c4 < NCH/4; ++c4) {
        int4 v = *(const int4*)(ccnt + qi*NCH + c4*4);
        total += v.x + v.y + v.z + v.w;
        mx = max(mx, max(max(v.x, v.y), max(v.z, v.w)));
        int bb = c4*4;
        off0 += (bb+0 < c0 ? v.x : 0) + (bb+1 < c0 ? v.y : 0)
              + (bb+2 < c0 ? v.z : 0) + (bb+3 < c0 ? v.w : 0);
    }
    bool bad = (total < KNN + 1) || (mx > SLOTS) || (total > LCAP);
    if (bad && sub == 0) {                       // rare: block-parallel fallback
        int p = atomicAdd(fbcnt, 1);
        fblist[p] = qi;
    }

    const float4* vb = vb4 + b * N;
    float4 q = vb[i];
    if (!bad) {
        const unsigned short* mycand = cand + (size_t)qi * CAP;
        int off = off0;
#pragma unroll
        for (int u = 0; u < 2; ++u) {
            int c = c0 + u;
            int nc = ccnt[qi * NCH + c];         // L1-resident reload (no local array)
            const unsigned short* cp = mycand + c * SLOTS;
            if (nc > 0) {
                GRP4W(cp, 0);
                if (nc > 4) {
                    GRP4W(cp, 4);
                    if (nc > 8) GRP4W(cp, 8);
                }
            }
            off += nc;
        }
    }
    __syncthreads();
    if (bad) return;

    // phase 2: rank my 6 strided positions against all keys
    ull kp[6];
#pragma unroll
    for (int t = 0; t < 6; ++t) {
        int p = sub + 16*t;
        kp[t] = (p < total) ? lkeys[kb + p] : ~0ull;   // sentinel rank = total > 16
    }
    int rank[6];
#pragma unroll
    for (int t = 0; t < 6; ++t) rank[t] = 0;
    for (int j = 0; j < total; ++j) {
        ull kj = lkeys[kb + j];                  // 16-lane broadcast read
#pragma unroll
        for (int t = 0; t < 6; ++t)
            rank[t] += (kj < kp[t]) ? 1 : 0;
    }
    int* oi = idxout + (size_t)qi * KNN;
#pragma unroll
    for (int t = 0; t < 6; ++t)
        if (rank[t] >= 1 && rank[t] <= KNN)      // rank 0 = self, excluded
            oi[rank[t]-1] = (int)(kp[t] & 0xffffffffu);
}

// ------------------------------------------------- exact BLOCK-parallel fallback
__global__ void k_fallback(const float4* __restrict__ vb4, const int* __restrict__ fbcnt,
                           const int* __restrict__ fblist, int* __restrict__ idxout) {
    __shared__ ull heap[16*256];                 // [t][tid], 32KB
    int nfb = *fbcnt;
    int tid = threadIdx.x;
    int lane = tid & 63, wv = tid >> 6;
    for (int w = blockIdx.x; w < nfb; w += gridDim.x) {
        int qi = fblist[w];
        int b = qi >> 13, i = qi & (N-1);
        const float4* vb = vb4 + b * N;
        float4 q = vb[i];
        DECL16;
        for (int s = 0; s < N/256; ++s) {        // 32 coalesced iterations
            int j = tid + s*256;
            if (j == i) continue;
            float d = dist2(q, vb[j]);
            ull nk = ((ull)__float_as_uint(d) << 32) | (unsigned)j;
            INS16(nk);
        }
        heap[0*256+tid]=K0;   heap[1*256+tid]=K1;   heap[2*256+tid]=K2;   heap[3*256+tid]=K3;
        heap[4*256+tid]=K4;   heap[5*256+tid]=K5;   heap[6*256+tid]=K6;   heap[7*256+tid]=K7;
        heap[8*256+tid]=K8;   heap[9*256+tid]=K9;   heap[10*256+tid]=K10; heap[11*256+tid]=K11;
        heap[12*256+tid]=K12; heap[13*256+tid]=K13; heap[14*256+tid]=K14; heap[15*256+tid]=K15;
        __syncthreads();
        if (wv == 0) {
            int l0 = lane*4, l1 = lane*4+1, l2 = lane*4+2, l3 = lane*4+3;
            int p0 = 0, p1 = 0, p2 = 0, p3 = 0;
            int* oi = idxout + (size_t)qi * KNN;
            for (int r = 0; r < KNN; ++r) {
                ull h0 = (p0 < 16) ? heap[p0*256 + l0] : ~0ull;
                ull h1 = (p1 < 16) ? heap[p1*256 + l1] : ~0ull;
                ull h2 = (p2 < 16) ? heap[p2*256 + l2] : ~0ull;
                ull h3 = (p3 < 16) ? heap[p3*256 + l3] : ~0ull;
                ull a01 = h0 < h1 ? h0 : h1;
                ull a23 = h2 < h3 ? h2 : h3;
                ull h   = a01 < a23 ? a01 : a23;
                ull m = h;
#pragma unroll
                for (int s = 1; s < 64; s <<= 1) {
                    ull o = __shfl_xor(m, s, 64);
                    m = (o < m) ? o : m;
                }
                if (h == m && m != ~0ull) {      // unique owner advances one list
                    if      (h0 == m) p0++;
                    else if (h1 == m) p1++;
                    else if (h2 == m) p2++;
                    else              p3++;
                }
                if (lane == r) oi[r] = (int)(m & 0xffffffffu);
            }
        }
        __syncthreads();
    }
}

// ------------------------------------------------- graph conv feature (n,128)
// 2 points per block (256 threads): halves block count vs 1-point version.
__global__ void k_feature(const float4* __restrict__ vb4, const float4* __restrict__ sup4,
                          const int* __restrict__ idx, float* __restrict__ feat) {
    int b = blockIdx.y, i0 = blockIdx.x * 2;
    __shared__ float4 dirn[2*KNN];
    const float4* vb = vb4 + b * N;
    int tid = threadIdx.x;
    if (tid < 2*KNN) {
        int p2 = tid >> 4, K = tid & 15;
        int i = i0 + p2;
        int j = idx[(size_t)(b*N + i)*KNN + K];
        float4 q = vb[i], p = vb[j];
        float dx = p.x - q.x, dy = p.y - q.y, dz = p.z - q.z;
        float inv = 1.f / fmaxf(sqrtf(fmaf(dx, dx, fmaf(dy, dy, dz*dz))), 1e-12f);
        dirn[tid] = make_float4(dx*inv, dy*inv, dz*inv, 0.f);
    }
    __syncthreads();
    int k = tid & 127;
    int p2 = tid >> 7;
    int i = i0 + p2;
    float acc = 0.f;
#pragma unroll
    for (int s = 0; s < SUP; ++s) {
        float4 sv = sup4[s*KC + k];
        float m = 0.f;                            // relu folded into max
#pragma unroll
        for (int K = 0; K < KNN; ++K) {
            float4 dn = dirn[p2*KNN + K];
            float t = fmaf(dn.x, sv.x, fmaf(dn.y, sv.y, dn.z*sv.z));
            m = fmaxf(m, t);
        }
        acc += m;
    }
    feat[(size_t)(b*N + i)*KC + k] = acc * (1.f/SUP);
}

// ------------------------------------------------- neighbor-max + partial mean
__global__ void k_nbmax(const float* __restrict__ feat, const int* __restrict__ idx,
                        float* __restrict__ partial) {
    int b = blockIdx.y;
    int p0 = blockIdx.x * PPB;
    int k = threadIdx.x;
    const float* fb = feat + (size_t)b*N*KC;
    float sum = 0.f;
    for (int p = 0; p < PPB; ++p) {
        const int* ii = idx + (size_t)(b*N + p0 + p) * KNN;
        float m = -3.4e38f;
#pragma unroll
        for (int K = 0; K < KNN; ++K)
            m = fmaxf(m, fb[(size_t)ii[K]*KC + k]);
        sum += m;
    }
    partial[(size_t)(b*(N/PPB) + blockIdx.x)*KC + k] = sum;
}

// ------------------------------------------------- stage-1 reduction (parallel)
// 64 blocks/batch x 128 threads: each block sums 32 consecutive partial rows.
__global__ void k_gred(const float* __restrict__ partial, float* __restrict__ partial2) {
    int b = blockIdx.y, j = blockIdx.x, k = threadIdx.x;
    const float* p = partial + ((size_t)(b*(N/PPB) + j*32))*KC + k;
    float s0 = 0.f, s1 = 0.f, s2 = 0.f, s3 = 0.f;
#pragma unroll
    for (int t = 0; t < 32; t += 4) {
        s0 += p[(t+0)*KC]; s1 += p[(t+1)*KC];
        s2 += p[(t+2)*KC]; s3 += p[(t+3)*KC];
    }
    partial2[(size_t)(b*GR1 + j)*KC + k] = (s0 + s1) + (s2 + s3);
}

// ------------------------------------------------- global vec + W2 fold
__global__ void k_global(const float* __restrict__ partial2, const float* __restrict__ wconv,
                         float* __restrict__ gconst) {
    int b = blockIdx.x, k = threadIdx.x;
    float s0 = 0.f, s1 = 0.f, s2 = 0.f, s3 = 0.f;
    const float* p = partial2 + (size_t)b*GR1*KC + k;
#pragma unroll
    for (int q = 0; q < GR1; q += 4) {
        s0 += p[(q+0)*KC]; s1 += p[(q+1)*KC];
        s2 += p[(q+2)*KC]; s3 += p[(q+3)*KC];
    }
    __shared__ float fg[KC];
    fg[k] = ((s0 + s1) + (s2 + s3)) * (1.f/N);
    __syncthreads();
    float acc = 0.f;
    for (int c = 0; c < KC; ++c)
        acc = fmaf(fg[c], wconv[k*2*KC + KC + c], acc);
    gconst[b*KC + k] = acc;
}

// ------------------------------------------------- epilogue GEMM + STE + add
// OPB=16: halves block count and halves per-launch wt4 L2 traffic (64KB/block).
__global__ void k_out(const float* __restrict__ feat, const float4* __restrict__ wt4,
                      const float4* __restrict__ wste4, const float4* __restrict__ vb4,
                      const float* __restrict__ gconst, float* __restrict__ out) {
    int p0 = blockIdx.x * OPB;
    int k = threadIdx.x;
    float acc[OPB];
#pragma unroll
    for (int p = 0; p < OPB; ++p) acc[p] = 0.f;
#pragma unroll 2
    for (int c4 = 0; c4 < KC/4; ++c4) {
        float4 w = wt4[c4*KC + k];
#pragma unroll
        for (int p = 0; p < OPB; ++p) {
            const float4 f = *(const float4*)(feat + (size_t)(p0 + p)*KC + c4*4);
            acc[p] = fmaf(f.x, w.x, fmaf(f.y, w.y, fmaf(f.z, w.z, fmaf(f.w, w.w, acc[p]))));
        }
    }
    float4 ws = wste4[k];
#pragma unroll
    for (int p = 0; p < OPB; ++p) {
        int pt = p0 + p;
        int b = pt >> 13;                        // / N
        float4 v = vb4[pt];
        float fste = fmaf(v.x, ws.x, fmaf(v.y, ws.y, v.z*ws.z));
        out[(size_t)pt*KC + k] = acc[p] + gconst[b*KC + k] + feat[(size_t)pt*KC + k] + fste;
    }
}

extern "C" void kernel_launch(void* const* d_in, const int* in_sizes, int n_in,
                              void* d_out, int out_size, void* d_ws, size_t ws_size,
                              hipStream_t stream) {
    const float* verts = (const float*)d_in[0];
    const float* dirs  = (const float*)d_in[1];
    const float* wste  = (const float*)d_in[2];
    const float* wconv = (const float*)d_in[3];
    float* out = (float*)d_out;

    // workspace layout; cand (u16) is dead after select/fallback and aliased as feat
    float* ws = (float*)d_ws;
    float4* vb4   = (float4*)ws;                  // BS*N
    float4* sup4  = vb4 + BS*N;                   // SK
    float4* wste4 = sup4 + SK;                    // KC
    float4* wt4   = wste4 + KC;                   // 32*KC
    float*  thr   = (float*)(wt4 + 32*KC);        // BS*N
    int*    ccnt  = (int*)(thr + BS*N);           // BS*N*NCH (2MB)
    int*    fbcnt = ccnt + BS*N*NCH;              // 16 (use [0])
    int*    fblist= fbcnt + 16;                   // BS*N
    unsigned short* cand = (unsigned short*)(fblist + BS*N);  // BS*N*CAP u16 (12.6MB)
    float*  feat  = (float*)cand;                 // BS*N*KC floats (8MB alias)
    int*    idx   = (int*)(cand + (size_t)BS*N*CAP);     // BS*N*KNN
    float*  partial = (float*)(idx + (size_t)BS*N*KNN);  // BS*(N/PPB)*KC (2MB)
    float*  partial2= partial + (size_t)BS*(N/PPB)*KC;   // BS*GR1*KC (64KB)
    float*  gconst  = partial2 + (size_t)BS*GR1*KC;      // BS*KC

    // fbcnt is zeroed by k_prep (no memset node)
    k_prep<<<(BS*N + SK + KC + 32*KC + 255)/256, 256, 0, stream>>>(verts, dirs, wste, wconv,
                                                                   vb4, sup4, wste4, wt4, fbcnt);
    k_thr<<<dim3(N/16, BS), 256, 0, stream>>>(vb4, thr);
    k_append<<<dim3(N/QG, NCH, BS), 256, 0, stream>>>(vb4, thr, ccnt, cand);
    k_select<<<dim3(N/16, BS), 256, 0, stream>>>(vb4, ccnt, cand, idx, fbcnt, fblist);
    k_fallback<<<256, 256, 0, stream>>>(vb4, fbcnt, fblist, idx);
    k_feature<<<dim3(N/2, BS), 256, 0, stream>>>(vb4, sup4, idx, feat);
    k_nbmax<<<dim3(N/PPB, BS), KC, 0, stream>>>(feat, idx, partial);
    k_gred<<<dim3(GR1, BS), KC, 0, stream>>>(partial, partial2);
    k_global<<<BS, KC, 0, stream>>>(partial2, wconv, gconst);
    k_out<<<BS*N/OPB, KC, 0, stream>>>(feat, wt4, wste4, vb4, gconst, out);
}

// Round 20
// 165.641 us; speedup vs baseline: 1.2050x; 1.2050x over previous
//
#include <hip/hip_runtime.h>
#include <math.h>

#define N     8192
#define BS    2
#define KNN   16
#define SUP   7
#define KC    128
#define SK    (SUP*KC)   // 896
#define NCH   32
#define CH    (N/NCH)    // 256
#define SLOTS 12
#define CAP   (NCH*SLOTS) // 384 u16 slots = 768B/query
#define QG    256
#define PPB   4
#define OPB   8
#define LCAP  120         // LDS key capacity per query (incl. self)
#define LSTR  122         // padded stride per query
#define GR1   64          // stage-1 reduction blocks per batch (32 rows each)

typedef unsigned long long ull;
typedef unsigned short ushort4v __attribute__((ext_vector_type(4)));

__device__ __forceinline__ float dist2(float4 a, float4 b) {
    float dx = a.x - b.x, dy = a.y - b.y, dz = a.z - b.z;
    return fmaf(dx, dx, fmaf(dy, dy, dz * dz));
}

// sorted-insert chain over 16 NAMED u64 registers (fallback path only)
#define SW(Kt) { ull _lo = (Kt < _n) ? Kt : _n; ull _hi = (Kt < _n) ? _n : Kt; Kt = _lo; _n = _hi; }
#define INS16(NK) do { ull _n = (NK); if (_n < K15) { \
    SW(K0) SW(K1) SW(K2) SW(K3) SW(K4) SW(K5) SW(K6) SW(K7) \
    SW(K8) SW(K9) SW(K10) SW(K11) SW(K12) SW(K13) SW(K14) SW(K15) } } while(0)

#define DECL16 ull K0=~0ull,K1=~0ull,K2=~0ull,K3=~0ull,K4=~0ull,K5=~0ull,K6=~0ull,K7=~0ull, \
                   K8=~0ull,K9=~0ull,K10=~0ull,K11=~0ull,K12=~0ull,K13=~0ull,K14=~0ull,K15=~0ull;

// ---------------------------------------------------------------- prep
// vb4.w = |p|^2 / 2; also zeroes fbcnt (replaces the memset graph node).
__global__ void k_prep(const float* __restrict__ verts, const float* __restrict__ dirs,
                       const float* __restrict__ wste, const float* __restrict__ wconv,
                       float4* __restrict__ vb4, float4* __restrict__ sup4,
                       float4* __restrict__ wste4, float4* __restrict__ wt4,
                       int* __restrict__ fbcnt) {
    int t = blockIdx.x * blockDim.x + threadIdx.x;
    if (t < 16) fbcnt[t] = 0;
    if (t < BS * N) {
        float x = verts[t*3], y = verts[t*3+1], z = verts[t*3+2];
        vb4[t] = make_float4(x, y, z, 0.5f * fmaf(x, x, fmaf(y, y, z*z)));
    }
    int u = t - BS * N;
    if (u >= 0 && u < SK) {
        float x = dirs[u], y = dirs[SK + u], z = dirs[2*SK + u];
        float inv = 1.f / fmaxf(sqrtf(fmaf(x, x, fmaf(y, y, z*z))), 1e-12f);
        sup4[u] = make_float4(x*inv, y*inv, z*inv, 0.f);
    }
    int v = u - SK;
    if (v >= 0 && v < KC)
        wste4[v] = make_float4(wste[v*3], wste[v*3+1], wste[v*3+2], 0.f);
    int w = v - KC;
    if (w >= 0 && w < 32*KC) {
        int c4 = w >> 7, k = w & 127;
        const float* r = wconv + k*2*KC + c4*4;   // W1 half, transposed to [c4][k]
        wt4[w] = make_float4(r[0], r[1], r[2], r[3]);
    }
}

// ------------------------------------------------- calibrated per-query radius
// 16 subs/query (4 waves/SIMD). LDS sample: SB=[0,2048), SA[t]=SB[4t].
// Phase A: 32-iter sorted-4 ladders + 4-stage shfl bitonic merge -> t4.
// Phase B: 128-iter count. thr = t4 * (14/c)^(1/3): solves 4c*(thr/t4)^3 = 56
// -> E[#pass over N] = 56 (target raised 48->56 to collapse the fallback-rate
// tail from thr noise; c-noise still cancels to first order).
__global__ void k_thr(const float4* __restrict__ vb4, float* __restrict__ thr) {
    __shared__ float4 SB[2048];
    __shared__ float4 SA[512];
    int b = blockIdx.y;
    int tid = threadIdx.x;
    const float4* vb = vb4 + b * N;
#pragma unroll
    for (int s = 0; s < 8; ++s)                  // coalesced 32KB stage
        SB[tid + 256*s] = vb[tid + 256*s];
    __syncthreads();
#pragma unroll
    for (int s = 0; s < 2; ++s) {                // derive phase-A subset
        int t = tid + 256*s;
        SA[t] = SB[4*t];
    }
    __syncthreads();
    int sub = tid & 15;
    int i = blockIdx.x * 16 + (tid >> 4);
    float4 q = vb[i];
    float b0 = 3.4e38f, b1 = 3.4e38f, b2 = 3.4e38f, b3 = 3.4e38f;
#pragma unroll 8
    for (int s = 0; s < 32; ++s) {
        int t = s * 16 + sub;
        float d = dist2(q, SA[t]);
        if (4*t == i) d = 3.4e38f;               // self-exclude
        float t0 = fminf(b0, d); float r = fmaxf(b0, d); b0 = t0;
        float t1 = fminf(b1, r); r = fmaxf(b1, r); b1 = t1;
        float t2 = fminf(b2, r); r = fmaxf(b2, r); b2 = t2;
        b3 = fminf(b3, r);
    }
#pragma unroll
    for (int st = 1; st < 16; st <<= 1) {        // merge sorted-4 lists across subs
        float c0 = __shfl_xor(b0, st, 64);
        float c1 = __shfl_xor(b1, st, 64);
        float c2 = __shfl_xor(b2, st, 64);
        float c3 = __shfl_xor(b3, st, 64);
        float m0 = fminf(b0, c3), m1 = fminf(b1, c2);
        float m2 = fminf(b2, c1), m3 = fminf(b3, c0);
        float x0 = fminf(m0, m2), x2 = fmaxf(m0, m2);
        float x1 = fminf(m1, m3), x3 = fmaxf(m1, m3);
        b0 = fminf(x0, x1); b1 = fmaxf(x0, x1);
        b2 = fminf(x2, x3); b3 = fmaxf(x2, x3);
    }
    float t4 = b3;
    int c = 0;
#pragma unroll 8
    for (int s = 0; s < 128; ++s) {
        int p = s * 16 + sub;
        float d = dist2(q, SB[p]);
        c += (d <= t4 && p != i) ? 1 : 0;
    }
    c += __shfl_xor(c, 1, 64);
    c += __shfl_xor(c, 2, 64);
    c += __shfl_xor(c, 4, 64);
    c += __shfl_xor(c, 8, 64);                   // c >= 4 (A-winners are in B)
    if (sub == 0) {
        float f = __powf(14.0f / (float)c, 0.3333333f);
        thr[b*N + i] = t4 * f;
    }
}

// ------------------------------------------------- filtered candidate append
// Dot-form filter: q.p - |p|^2/2 >= (|q|^2 - thr)/2  <=>  |q-p|^2 <= thr.
// SELF IS INCLUDED and excluded later in select via rank shift.
// blockIdx.y-based chunk base -> wave-uniform addresses -> scalar-pipe s_load.
__global__ void k_append(const float4* __restrict__ vb4, const float* __restrict__ thr,
                         int* __restrict__ ccnt, unsigned short* __restrict__ cand) {
    int b = blockIdx.z, qg = blockIdx.x, c = blockIdx.y;
    const float4* vb = vb4 + b * N;
    int base = c * CH;
    int i = qg * QG + threadIdx.x;
    int qi = b*N + i;
    float4 q = vb[i];
    float h = q.w - 0.5f * thr[qi];              // (|q|^2 - thr)/2
    unsigned short* mycand = cand + ((size_t)qi * NCH + c) * SLOTS;
    const float4* pts = vb + base;
    int p = 0;
#pragma unroll 8
    for (int j = 0; j < CH; ++j) {
        float4 pt = pts[j];                      // wave-uniform address -> scalar pipe
        float lhs = fmaf(q.x, pt.x, fmaf(q.y, pt.y, fmaf(q.z, pt.z, -pt.w)));
        if (lhs >= h) {
            mycand[p < SLOTS ? p : SLOTS-1] = (unsigned short)(base + j);
            p++;
        }
    }
    ccnt[qi * NCH + c] = p;                      // actual count (>SLOTS flags overflow)
}

// ------------------------------------------------- exact top-16: rank-based
// 16 subs/query (4 waves/SIMD), 2 chunks each. Phase 1: gather keys to LDS.
// Phase 2: 8 strided positions/thread (covers LCAP=120); rank = #{keys < mine}.
// Self rank 0; neighbors ranks 1..16 -> oi[rank-1].
#define GRP4W(CP, SOFF) { \
    ushort4v gv = *(const ushort4v*)((CP) + (SOFF)); \
    int jj[4]; \
    _Pragma("unroll") for (int s = 0; s < 4; ++s) jj[s] = (int)gv[s]; \
    float4 pv[4]; \
    _Pragma("unroll") for (int s = 0; s < 4; ++s) pv[s] = vb[jj[s] & (N-1)]; \
    _Pragma("unroll") for (int s = 0; s < 4; ++s) { \
        if ((SOFF + s) < nc) { \
            float d = dist2(q, pv[s]); \
            lkeys[kb + off + SOFF + s] = ((ull)__float_as_uint(d) << 32) | (unsigned)jj[s]; \
        } \
    } }

__global__ void k_select(const float4* __restrict__ vb4, const int* __restrict__ ccnt,
                         const unsigned short* __restrict__ cand, int* __restrict__ idxout,
                         int* __restrict__ fbcnt, int* __restrict__ fblist) {
    __shared__ ull lkeys[16 * LSTR];             // 15.25 KB
    int b = blockIdx.y;
    int tid = threadIdx.x;
    int sub = tid & 15;
    int ql = tid >> 4;                           // 0..15
    int i = blockIdx.x * 16 + ql;
    int qi = b*N + i;
    int kb = ql * LSTR;
    int c0 = 2*sub;

    int total = 0, mx = 0, off0 = 0;
#pragma unroll
    for (int c4 = 0; c4 < NCH/4; ++c4) {
        int4 v = *(const int4*)(ccnt + qi*NCH + c4*4);
        total += v.x + v.y + v.z + v.w;
        mx = max(mx, max(max(v.x, v.y), max(v.z, v.w)));
        int bb = c4*4;
        off0 += (bb+0 < c0 ? v.x : 0) + (bb+1 < c0 ? v.y : 0)
              + (bb+2 < c0 ? v.z : 0) + (bb+3 < c0 ? v.w : 0);
    }
    bool bad = (total < KNN + 1) || (mx > SLOTS) || (total > LCAP);
    if (bad && sub == 0) {                       // rare: block-parallel fallback
        int p = atomicAdd(fbcnt, 1);
        fblist[p] = qi;
    }

    const float4* vb = vb4 + b * N;
    float4 q = vb[i];
    if (!bad) {
        const unsigned short* mycand = cand + (size_t)qi * CAP;
        int off = off0;
#pragma unroll
        for (int u = 0; u < 2; ++u) {
            int c = c0 + u;
            int nc = ccnt[qi * NCH + c];         // L1-resident reload (no local array)
            const unsigned short* cp = mycand + c * SLOTS;
            if (nc > 0) {
                GRP4W(cp, 0);
                if (nc > 4) {
                    GRP4W(cp, 4);
                    if (nc > 8) GRP4W(cp, 8);
                }
            }
            off += nc;
        }
    }
    __syncthreads();
    if (bad) return;

    // phase 2: rank my 8 strided positions against all keys
    ull kp[8];
#pragma unroll
    for (int t = 0; t < 8; ++t) {
        int p = sub + 16*t;
        kp[t] = (p < total) ? lkeys[kb + p] : ~0ull;   // sentinel rank = total > 16
    }
    int rank[8];
#pragma unroll
    for (int t = 0; t < 8; ++t) rank[t] = 0;
    for (int j = 0; j < total; ++j) {
        ull kj = lkeys[kb + j];                  // 16-lane broadcast read
#pragma unroll
        for (int t = 0; t < 8; ++t)
            rank[t] += (kj < kp[t]) ? 1 : 0;
    }
    int* oi = idxout + (size_t)qi * KNN;
#pragma unroll
    for (int t = 0; t < 8; ++t)
        if (rank[t] >= 1 && rank[t] <= KNN)      // rank 0 = self, excluded
            oi[rank[t]-1] = (int)(kp[t] & 0xffffffffu);
}

// ------------------------------------------------- exact BLOCK-parallel fallback
__global__ void k_fallback(const float4* __restrict__ vb4, const int* __restrict__ fbcnt,
                           const int* __restrict__ fblist, int* __restrict__ idxout) {
    __shared__ ull heap[16*256];                 // [t][tid], 32KB
    int nfb = *fbcnt;
    int tid = threadIdx.x;
    int lane = tid & 63, wv = tid >> 6;
    for (int w = blockIdx.x; w < nfb; w += gridDim.x) {
        int qi = fblist[w];
        int b = qi >> 13, i = qi & (N-1);
        const float4* vb = vb4 + b * N;
        float4 q = vb[i];
        DECL16;
        for (int s = 0; s < N/256; ++s) {        // 32 coalesced iterations
            int j = tid + s*256;
            if (j == i) continue;
            float d = dist2(q, vb[j]);
            ull nk = ((ull)__float_as_uint(d) << 32) | (unsigned)j;
            INS16(nk);
        }
        heap[0*256+tid]=K0;   heap[1*256+tid]=K1;   heap[2*256+tid]=K2;   heap[3*256+tid]=K3;
        heap[4*256+tid]=K4;   heap[5*256+tid]=K5;   heap[6*256+tid]=K6;   heap[7*256+tid]=K7;
        heap[8*256+tid]=K8;   heap[9*256+tid]=K9;   heap[10*256+tid]=K10; heap[11*256+tid]=K11;
        heap[12*256+tid]=K12; heap[13*256+tid]=K13; heap[14*256+tid]=K14; heap[15*256+tid]=K15;
        __syncthreads();
        if (wv == 0) {
            int l0 = lane*4, l1 = lane*4+1, l2 = lane*4+2, l3 = lane*4+3;
            int p0 = 0, p1 = 0, p2 = 0, p3 = 0;
            int* oi = idxout + (size_t)qi * KNN;
            for (int r = 0; r < KNN; ++r) {
                ull h0 = (p0 < 16) ? heap[p0*256 + l0] : ~0ull;
                ull h1 = (p1 < 16) ? heap[p1*256 + l1] : ~0ull;
                ull h2 = (p2 < 16) ? heap[p2*256 + l2] : ~0ull;
                ull h3 = (p3 < 16) ? heap[p3*256 + l3] : ~0ull;
                ull a01 = h0 < h1 ? h0 : h1;
                ull a23 = h2 < h3 ? h2 : h3;
                ull h   = a01 < a23 ? a01 : a23;
                ull m = h;
#pragma unroll
                for (int s = 1; s < 64; s <<= 1) {
                    ull o = __shfl_xor(m, s, 64);
                    m = (o < m) ? o : m;
                }
                if (h == m && m != ~0ull) {      // unique owner advances one list
                    if      (h0 == m) p0++;
                    else if (h1 == m) p1++;
                    else if (h2 == m) p2++;
                    else              p3++;
                }
                if (lane == r) oi[r] = (int)(m & 0xffffffffu);
            }
        }
        __syncthreads();
    }
}

// ------------------------------------------------- graph conv feature (n,128)
__global__ void k_feature(const float4* __restrict__ vb4, const float4* __restrict__ sup4,
                          const int* __restrict__ idx, float* __restrict__ feat) {
    int b = blockIdx.y, i = blockIdx.x;
    __shared__ float4 dirn[KNN];
    const float4* vb = vb4 + b * N;
    if (threadIdx.x < KNN) {
        int j = idx[(size_t)(b*N + i)*KNN + threadIdx.x];
        float4 q = vb[i], p = vb[j];
        float dx = p.x - q.x, dy = p.y - q.y, dz = p.z - q.z;
        float inv = 1.f / fmaxf(sqrtf(fmaf(dx, dx, fmaf(dy, dy, dz*dz))), 1e-12f);
        dirn[threadIdx.x] = make_float4(dx*inv, dy*inv, dz*inv, 0.f);
    }
    __syncthreads();
    int k = threadIdx.x;
    float acc = 0.f;
#pragma unroll
    for (int s = 0; s < SUP; ++s) {
        float4 sv = sup4[s*KC + k];
        float m = 0.f;                            // relu folded into max
#pragma unroll
        for (int K = 0; K < KNN; ++K) {
            float4 dn = dirn[K];
            float t = fmaf(dn.x, sv.x, fmaf(dn.y, sv.y, dn.z*sv.z));
            m = fmaxf(m, t);
        }
        acc += m;
    }
    feat[(size_t)(b*N + i)*KC + k] = acc * (1.f/SUP);
}

// ------------------------------------------------- neighbor-max + partial mean
__global__ void k_nbmax(const float* __restrict__ feat, const int* __restrict__ idx,
                        float* __restrict__ partial) {
    int b = blockIdx.y;
    int p0 = blockIdx.x * PPB;
    int k = threadIdx.x;
    const float* fb = feat + (size_t)b*N*KC;
    float sum = 0.f;
    for (int p = 0; p < PPB; ++p) {
        const int* ii = idx + (size_t)(b*N + p0 + p) * KNN;
        float m = -3.4e38f;
#pragma unroll
        for (int K = 0; K < KNN; ++K)
            m = fmaxf(m, fb[(size_t)ii[K]*KC + k]);
        sum += m;
    }
    partial[(size_t)(b*(N/PPB) + blockIdx.x)*KC + k] = sum;
}

// ------------------------------------------------- stage-1 reduction (parallel)
// 64 blocks/batch x 128 threads: each block sums 32 consecutive partial rows.
__global__ void k_gred(const float* __restrict__ partial, float* __restrict__ partial2) {
    int b = blockIdx.y, j = blockIdx.x, k = threadIdx.x;
    const float* p = partial + ((size_t)(b*(N/PPB) + j*32))*KC + k;
    float s0 = 0.f, s1 = 0.f, s2 = 0.f, s3 = 0.f;
#pragma unroll
    for (int t = 0; t < 32; t += 4) {
        s0 += p[(t+0)*KC]; s1 += p[(t+1)*KC];
        s2 += p[(t+2)*KC]; s3 += p[(t+3)*KC];
    }
    partial2[(size_t)(b*GR1 + j)*KC + k] = (s0 + s1) + (s2 + s3);
}

// ------------------------------------------------- global vec + W2 fold
__global__ void k_global(const float* __restrict__ partial2, const float* __restrict__ wconv,
                         float* __restrict__ gconst) {
    int b = blockIdx.x, k = threadIdx.x;
    float s0 = 0.f, s1 = 0.f, s2 = 0.f, s3 = 0.f;
    const float* p = partial2 + (size_t)b*GR1*KC + k;
#pragma unroll
    for (int q = 0; q < GR1; q += 4) {
        s0 += p[(q+0)*KC]; s1 += p[(q+1)*KC];
        s2 += p[(q+2)*KC]; s3 += p[(q+3)*KC];
    }
    __shared__ float fg[KC];
    fg[k] = ((s0 + s1) + (s2 + s3)) * (1.f/N);
    __syncthreads();
    float acc = 0.f;
    for (int c = 0; c < KC; ++c)
        acc = fmaf(fg[c], wconv[k*2*KC + KC + c], acc);
    gconst[b*KC + k] = acc;
}

// ------------------------------------------------- epilogue GEMM + STE + add
__global__ void k_out(const float* __restrict__ feat, const float4* __restrict__ wt4,
                      const float4* __restrict__ wste4, const float4* __restrict__ vb4,
                      const float* __restrict__ gconst, float* __restrict__ out) {
    int p0 = blockIdx.x * OPB;
    int k = threadIdx.x;
    float acc[OPB];
#pragma unroll
    for (int p = 0; p < OPB; ++p) acc[p] = 0.f;
#pragma unroll 4
    for (int c4 = 0; c4 < KC/4; ++c4) {
        float4 w = wt4[c4*KC + k];
#pragma unroll
        for (int p = 0; p < OPB; ++p) {
            const float4 f = *(const float4*)(feat + (size_t)(p0 + p)*KC + c4*4);
            acc[p] = fmaf(f.x, w.x, fmaf(f.y, w.y, fmaf(f.z, w.z, fmaf(f.w, w.w, acc[p]))));
        }
    }
    float4 ws = wste4[k];
#pragma unroll
    for (int p = 0; p < OPB; ++p) {
        int pt = p0 + p;
        int b = pt >> 13;                        // / N
        float4 v = vb4[pt];
        float fste = fmaf(v.x, ws.x, fmaf(v.y, ws.y, v.z*ws.z));
        out[(size_t)pt*KC + k] = acc[p] + gconst[b*KC + k] + feat[(size_t)pt*KC + k] + fste;
    }
}

extern "C" void kernel_launch(void* const* d_in, const int* in_sizes, int n_in,
                              void* d_out, int out_size, void* d_ws, size_t ws_size,
                              hipStream_t stream) {
    const float* verts = (const float*)d_in[0];
    const float* dirs  = (const float*)d_in[1];
    const float* wste  = (const float*)d_in[2];
    const float* wconv = (const float*)d_in[3];
    float* out = (float*)d_out;

    // workspace layout; cand (u16) is dead after select/fallback and aliased as feat
    float* ws = (float*)d_ws;
    float4* vb4   = (float4*)ws;                  // BS*N
    float4* sup4  = vb4 + BS*N;                   // SK
    float4* wste4 = sup4 + SK;                    // KC
    float4* wt4   = wste4 + KC;                   // 32*KC
    float*  thr   = (float*)(wt4 + 32*KC);        // BS*N
    int*    ccnt  = (int*)(thr + BS*N);           // BS*N*NCH (2MB)
    int*    fbcnt = ccnt + BS*N*NCH;              // 16 (use [0])
    int*    fblist= fbcnt + 16;                   // BS*N
    unsigned short* cand = (unsigned short*)(fblist + BS*N);  // BS*N*CAP u16 (12.6MB)
    float*  feat  = (float*)cand;                 // BS*N*KC floats (8MB alias)
    int*    idx   = (int*)(cand + (size_t)BS*N*CAP);     // BS*N*KNN
    float*  partial = (float*)(idx + (size_t)BS*N*KNN);  // BS*(N/PPB)*KC (2MB)
    float*  partial2= partial + (size_t)BS*(N/PPB)*KC;   // BS*GR1*KC (64KB)
    float*  gconst  = partial2 + (size_t)BS*GR1*KC;      // BS*KC

    // fbcnt is zeroed by k_prep (no memset node)
    k_prep<<<(BS*N + SK + KC + 32*KC + 255)/256, 256, 0, stream>>>(verts, dirs, wste, wconv,
                                                                   vb4, sup4, wste4, wt4, fbcnt);
    k_thr<<<dim3(N/16, BS), 256, 0, stream>>>(vb4, thr);
    k_append<<<dim3(N/QG, NCH, BS), 256, 0, stream>>>(vb4, thr, ccnt, cand);
    k_select<<<dim3(N/16, BS), 256, 0, stream>>>(vb4, ccnt, cand, idx, fbcnt, fblist);
    k_fallback<<<1024, 256, 0, stream>>>(vb4, fbcnt, fblist, idx);
    k_feature<<<dim3(N, BS), KC, 0, stream>>>(vb4, sup4, idx, feat);
    k_nbmax<<<dim3(N/PPB, BS), KC, 0, stream>>>(feat, idx, partial);
    k_gred<<<dim3(GR1, BS), KC, 0, stream>>>(partial, partial2);
    k_global<<<BS, KC, 0, stream>>>(partial2, wconv, gconst);
    k_out<<<BS*N/OPB, KC, 0, stream>>>(feat, wt4, wste4, vb4, gconst, out);
}